// Round 9
// baseline (259.442 us; speedup 1.0000x reference)
//
#include <hip/hip_runtime.h>
#include <cstdint>
#include <cstddef>

typedef unsigned short u16;
typedef __attribute__((ext_vector_type(8))) short short8;
typedef __attribute__((ext_vector_type(4))) float f32x4;
typedef __attribute__((ext_vector_type(4))) unsigned short u16x4;

#define B_ 4
#define T_ 2048
#define D_ 1024
#define H_ 16
#define HD_ 64

__device__ __forceinline__ u16 f2bf(float f) {
  union { float f; unsigned i; } v; v.f = f;
  unsigned r = (v.i + 0x7FFFu + ((v.i >> 16) & 1u)) >> 16;
  return (u16)r;
}

__device__ __forceinline__ unsigned cvt_pk_bf16(float lo, float hi) {
  unsigned r;
  asm("v_cvt_pk_bf16_f32 %0, %1, %2" : "=v"(r) : "v"(lo), "v"(hi));
  return r;
}

__device__ __forceinline__ void load_lds16(const void* g, void* l) {
  __builtin_amdgcn_global_load_lds(
      (const __attribute__((address_space(1))) void*)g,
      (__attribute__((address_space(3))) void*)l, 16, 0, 0);
}

#define RBAR() asm volatile("s_barrier" ::: "memory")
#define VMC(n) asm volatile("s_waitcnt vmcnt(" #n ")" ::: "memory")

// ---------------- fused preprocessing: cvt(x) + transpose(Wqkv) + transpose(Wproj) ----------------
__global__ __launch_bounds__(256)
void pre_all(const float* __restrict__ x, u16* __restrict__ xb,
             const float* __restrict__ Wqkv, u16* __restrict__ WqkvT,
             const float* __restrict__ Wproj, u16* __restrict__ WprojT) {
  __shared__ u16 t[32][33];
  const int bid = blockIdx.x;
  const int tid = threadIdx.x;
  if (bid < 8192) {
    const size_t i = ((size_t)bid * 256 + tid) * 4;
    const f32x4 v = *(const f32x4*)(x + i);
    union { unsigned u[2]; u16x4 v4; } o;
    o.u[0] = cvt_pk_bf16(v[0], v[1]);
    o.u[1] = cvt_pk_bf16(v[2], v[3]);
    *(u16x4*)(xb + i) = o.v4;
    return;
  }
  const float* src; u16* dst; int R, C, bx, by;
  if (bid < 11264) {
    const int tb = bid - 8192;
    bx = tb % 96; by = tb / 96; src = Wqkv; dst = WqkvT; R = 1024; C = 3072;
  } else {
    const int tb = bid - 11264;
    bx = tb & 31; by = tb >> 5; src = Wproj; dst = WprojT; R = 1024; C = 1024;
  }
  const int c0 = bx * 32, r0 = by * 32;
  const int lr = tid >> 5, lc = tid & 31;
#pragma unroll
  for (int p = 0; p < 4; ++p)
    t[lr + p * 8][lc] = f2bf(src[(size_t)(r0 + lr + p * 8) * C + c0 + lc]);
  __syncthreads();
#pragma unroll
  for (int p = 0; p < 4; ++p)
    dst[(size_t)(c0 + lr + p * 8) * R + r0 + lc] = t[lc][lr + p * 8];
}

// ---------------- 128x128 GEMM: 3-buf depth-2 pipeline + n-major XCD chunking + T2 swizzle ----------------
// K-loop identical to round 8. NEW: LDS-staged coalesced epilogues.
//   EPI==0, c<2 (Q,K): stage bf16 [m][n] in LDS ([128][136] u16), write 128B
//     contiguous rows Q[bh][t][0..63] as 8x dwordx4 per thread.
//   EPI==0, c==2 (Vt): stage [n][m] (packed b64 writes), write 128B runs Vt[bh][d][t..].
//   EPI==1: two 64-col passes through [128][68] f32, coalesced f32x4 row writes.
// Replaces 64x 2B (or 16x 4B) scattered global stores per thread (WRITE_SIZE 1.7x ideal).
template <int EPI>
__global__ __launch_bounds__(256)
void gemm_db(const u16* __restrict__ A, const u16* __restrict__ Bt,
             const float* __restrict__ bias, int K, int N,
             void* __restrict__ o0v, u16* __restrict__ o1, u16* __restrict__ o2) {
  __shared__ u16 smem[24576];    // 48KB: As = [0,12288), Bs = [12288,24576); epilogue reuses all
  const int tid = threadIdx.x;
  const int lane = tid & 63;
  const int w = tid >> 6;
  const int q = lane >> 4, col = lane & 15;

  const int id = blockIdx.y * gridDim.x + blockIdx.x;
  const int x = id & 7;                       // XCD (dispatch round-robin)
  const int c = id >> 3;                      // index within this XCD's chunk
  const int n0 = (c >> 3) * 128;              // n-panel-major within chunk
  const int m0 = ((x << 3) + (c & 7)) * 128;  // 8 m-panels per XCD

  const int wm = (w >> 1) * 64, wn = (w & 1) * 64;

  const int srow = tid >> 2;
  const int cb8 = ((tid & 3) ^ ((tid >> 3) & 3)) << 3;
  const u16* Ap = A + (size_t)(m0 + srow) * K + cb8;
  const u16* Bp = Bt + (size_t)(n0 + srow) * K + cb8;

  const int rs = (q ^ ((col >> 1) & 3)) << 3;

  f32x4 acc[4][4] = {};

  auto STAGE = [&](int b, int kb) {
    load_lds16(Ap + kb, &smem[b * 4096 + tid * 8]);
    load_lds16(Ap + (size_t)64 * K + kb, &smem[b * 4096 + 2048 + tid * 8]);
    load_lds16(Bp + kb, &smem[12288 + b * 4096 + tid * 8]);
    load_lds16(Bp + (size_t)64 * K + kb, &smem[12288 + b * 4096 + 2048 + tid * 8]);
  };

  const int NT = K >> 5;  // assumes NT >= 3
  STAGE(0, 0);
  STAGE(1, 32);
  int cur = 0, stg = 2;

  for (int t = 0; t < NT; ++t) {
    if (t + 2 < NT) {
      STAGE(stg, (t + 2) << 5);
      VMC(8);            // drain tile t's 4 loads; keep tiles t+1,t+2 in flight
    } else if (t + 1 < NT) {
      VMC(4);
    } else {
      VMC(0);
    }
    RBAR();              // BAR1: all waves' tile-t staging visible
    short8 af[4], bfr[4];
#pragma unroll
    for (int i = 0; i < 4; ++i)
      af[i] = *(const short8*)&smem[cur * 4096 + (wm + i * 16 + col) * 32 + rs];
#pragma unroll
    for (int j = 0; j < 4; ++j)
      bfr[j] = *(const short8*)&smem[12288 + cur * 4096 + (wn + j * 16 + col) * 32 + rs];
#pragma unroll
    for (int i = 0; i < 4; ++i)
#pragma unroll
      for (int j = 0; j < 4; ++j)
        acc[i][j] = __builtin_amdgcn_mfma_f32_16x16x32_bf16(af[i], bfr[j], acc[i][j], 0, 0, 0);
    RBAR();              // BAR2: reads of buf cur done before anyone re-stages it
    cur = (cur == 2) ? 0 : cur + 1;
    stg = (stg == 2) ? 0 : stg + 1;
  }
  // after BAR2 all waves are past their LDS reads -> smem reusable

  if constexpr (EPI == 0) {
    const int cc = n0 >> 10;            // whole block is one of {Q,K,Vt}
    if (cc < 2) {
      // ---- stage [m][n] bf16, stride 136 (272B = 16B-aligned rows) ----
#pragma unroll
      for (int j = 0; j < 4; ++j) {
        const int nn = wn + j * 16 + col;
        const float bv = bias[n0 + nn];
#pragma unroll
        for (int i = 0; i < 4; ++i)
#pragma unroll
          for (int r = 0; r < 4; ++r) {
            float v = acc[i][j][r] + bv;
            if (cc == 0) v *= 0.125f;
            smem[(wm + i * 16 + q * 4 + r) * 136 + nn] = f2bf(v);
          }
      }
      __syncthreads();
      // ---- coalesced write: thread -> (m = tid>>1, head-half = tid&1), 128B run ----
      const int mloc = tid >> 1, half = tid & 1;
      const int mrow = m0 + mloc;
      const int b = mrow >> 11, t = mrow & 2047;
      const int hh = ((n0 & 1023) >> 6) + half;
      const int bh = b * H_ + hh;
      u16* gdst = ((cc == 0) ? (u16*)o0v : o1) + ((size_t)bh * T_ + t) * HD_;
      const u16* lsrc = &smem[mloc * 136 + half * 64];
#pragma unroll
      for (int k2 = 0; k2 < 8; ++k2)
        *(short8*)&gdst[k2 * 8] = *(const short8*)&lsrc[k2 * 8];
    } else {
      // ---- stage [n][m] bf16 (packed b64 writes), stride 136 ----
#pragma unroll
      for (int j = 0; j < 4; ++j) {
        const int nn = wn + j * 16 + col;
        const float bv = bias[n0 + nn];
#pragma unroll
        for (int i = 0; i < 4; ++i) {
          union { unsigned u[2]; u16x4 v4; } pk;
          pk.u[0] = cvt_pk_bf16(acc[i][j][0] + bv, acc[i][j][1] + bv);
          pk.u[1] = cvt_pk_bf16(acc[i][j][2] + bv, acc[i][j][3] + bv);
          *(u16x4*)&smem[nn * 136 + wm + i * 16 + q * 4] = pk.v4;
        }
      }
      __syncthreads();
      // ---- coalesced write: thread -> (d-row = tid>>1, t-half = tid&1), 128B run ----
      const int nloc = tid >> 1, half = tid & 1;
      const int rem = (n0 & 1023) + nloc;
      const int hh = rem >> 6, dd = rem & 63;
      const int b = m0 >> 11, t0l = m0 & 2047;
      const int bh = b * H_ + hh;
      u16* gdst = o2 + ((size_t)bh * HD_ + dd) * T_ + t0l + half * 64;
      const u16* lsrc = &smem[nloc * 136 + half * 64];
#pragma unroll
      for (int k2 = 0; k2 < 8; ++k2)
        *(short8*)&gdst[k2 * 8] = *(const short8*)&lsrc[k2 * 8];
    }
  } else {
    // ---- fp32 out: two 64-col passes through [128][68] f32 ----
    float* Lf = (float*)smem;
    float* outp = (float*)o0v;
#pragma unroll
    for (int p = 0; p < 2; ++p) {
      if (p) __syncthreads();   // prior pass's reads done before overwrite
      if ((w & 1) == p) {
#pragma unroll
        for (int j = 0; j < 4; ++j) {
          const int nn = j * 16 + col;
          const float bv = bias[n0 + p * 64 + nn];
#pragma unroll
          for (int i = 0; i < 4; ++i)
#pragma unroll
            for (int r = 0; r < 4; ++r)
              Lf[(wm + i * 16 + q * 4 + r) * 68 + nn] = acc[i][j][r] + bv;
        }
      }
      __syncthreads();
      const int mloc = tid >> 1, half = tid & 1;
      float* gdst = outp + (size_t)(m0 + mloc) * N + n0 + p * 64 + half * 32;
      const float* lsrc = &Lf[mloc * 68 + half * 32];
#pragma unroll
      for (int k2 = 0; k2 < 8; ++k2)
        *(f32x4*)&gdst[k2 * 4] = *(const f32x4*)&lsrc[k2 * 4];
    }
  }
}

// ---------------- sparse causal attention (v3 — frozen) ----------------
__global__ __launch_bounds__(256)
void sparse_attn(const u16* __restrict__ Qb, const u16* __restrict__ Kb,
                 const u16* __restrict__ Vt, u16* __restrict__ Y) {
  __shared__ char smem[20480];           // P region; merge buffer overlaps after barrier
  u16* Pall = (u16*)smem;                // per-wave 64x40 u16 (5120 B)
  float* Obuf = (float*)smem;            // merge: [4 waves][65 cols][16 rows] f32 = 16640 B

  const int tid = threadIdx.x, lane = tid & 63, w = tid >> 6;
  const int q = lane >> 4, col = lane & 15;
  const int bh = blockIdx.x, qt = blockIdx.y;   // (bh,qt) for CU load balance
  const int b = bh >> 4, hh = bh & 15;
  const int qb = qt >> 2;                // 256-stride block index
  const int rb = (qt & 3) * 64;          // row base within stride block
  const int qg = qt * 64;                // global row base
  const u16* Qh = Qb + (size_t)bh * T_ * HD_;
  const u16* Kh = Kb + (size_t)bh * T_ * HD_;
  const u16* Vh = Vt + (size_t)bh * HD_ * T_;

  short8 qf[4][2];
#pragma unroll
  for (int i = 0; i < 4; ++i)
#pragma unroll
    for (int h2 = 0; h2 < 2; ++h2)
      qf[i][h2] = *(const short8*)&Qh[(size_t)(qg + i * 16 + col) * HD_ + h2 * 32 + q * 8];

  f32x4 o[4][4] = {};
  f32x4 lI[4] = {};
  const short8 ones = {0x3F80, 0x3F80, 0x3F80, 0x3F80, 0x3F80, 0x3F80, 0x3F80, 0x3F80};

  u16* P = Pall + w * 2560;

  const int ns = (qb + 1) >> 1;              // stripe chunks (2 stripe blocks each)
  const int L = ns + 2 * (qt & 3) + 2;       // + local chunks

  auto params = [&](int j, int& k0, int& k1, bool& mask1, int& localc) {
    if (j < ns) {
      k0 = (2 * j) * 256 + 240; k1 = k0 + 256;
      mask1 = (2 * j + 1 == qb); localc = -1;
    } else {
      const int c = j - ns;
      k0 = qb * 256 + c * 32; k1 = k0 + 16;
      mask1 = false; localc = c * 32;
    }
  };
  auto ldK = [&](int k0, int k1, short8* kf) {
    kf[0] = *(const short8*)&Kh[(size_t)(k0 + col) * HD_ + q * 8];
    kf[1] = *(const short8*)&Kh[(size_t)(k0 + col) * HD_ + 32 + q * 8];
    kf[2] = *(const short8*)&Kh[(size_t)(k1 + col) * HD_ + q * 8];
    kf[3] = *(const short8*)&Kh[(size_t)(k1 + col) * HD_ + 32 + q * 8];
  };

  int k0 = 0, k1 = 0, localc = -1;
  bool mask1 = false;
  short8 kf[4];
  if (w < L) { params(w, k0, k1, mask1, localc); ldK(k0, k1, kf); }

  for (int j = w; j < L; j += 4) {
    const int kvb = (q < 2) ? (k0 + q * 8) : (k1 + (q - 2) * 8);
    short8 vf[4];
#pragma unroll
    for (int dt = 0; dt < 4; ++dt)
      vf[dt] = *(const short8*)&Vh[(size_t)(dt * 16 + col) * T_ + kvb];
    int nk0 = 0, nk1 = 0, nlocalc = -1;
    bool nmask1 = false;
    short8 nkf[4];
    const bool hn = (j + 4) < L;
    if (hn) { params(j + 4, nk0, nk1, nmask1, nlocalc); ldK(nk0, nk1, nkf); }

#pragma unroll
    for (int rt = 0; rt < 4; ++rt) {
      f32x4 z = {0.f, 0.f, 0.f, 0.f};
      f32x4 s0 = __builtin_amdgcn_mfma_f32_16x16x32_bf16(qf[rt][0], kf[0], z, 0, 0, 0);
      s0 = __builtin_amdgcn_mfma_f32_16x16x32_bf16(qf[rt][1], kf[1], s0, 0, 0, 0);
      f32x4 s1 = __builtin_amdgcn_mfma_f32_16x16x32_bf16(qf[rt][0], kf[2], z, 0, 0, 0);
      s1 = __builtin_amdgcn_mfma_f32_16x16x32_bf16(qf[rt][1], kf[3], s1, 0, 0, 0);
#pragma unroll
      for (int r = 0; r < 4; ++r) {
        float p0 = __expf(s0[r]);
        float p1 = mask1 ? 0.f : __expf(s1[r]);
        if (localc >= 0) {
          const int qr = rb + rt * 16 + q * 4 + r;
          if (localc + col > qr) p0 = 0.f;
          if (localc + 16 + col > qr) p1 = 0.f;
        }
        const unsigned pc = cvt_pk_bf16(p0, p1);
        P[(rt * 16 + q * 4 + r) * 40 + col] = (u16)pc;
        P[(rt * 16 + q * 4 + r) * 40 + 16 + col] = (u16)(pc >> 16);
      }
    }
    asm volatile("s_waitcnt lgkmcnt(0)" ::: "memory");
    short8 pf[4];
#pragma unroll
    for (int rt = 0; rt < 4; ++rt)
      pf[rt] = *(const short8*)&P[(rt * 16 + col) * 40 + q * 8];
#pragma unroll
    for (int rt = 0; rt < 4; ++rt) {
#pragma unroll
      for (int dt = 0; dt < 4; ++dt)
        o[rt][dt] = __builtin_amdgcn_mfma_f32_16x16x32_bf16(pf[rt], vf[dt], o[rt][dt], 0, 0, 0);
      lI[rt] = __builtin_amdgcn_mfma_f32_16x16x32_bf16(pf[rt], ones, lI[rt], 0, 0, 0);
    }
    if (hn) {
      k0 = nk0; k1 = nk1; mask1 = nmask1; localc = nlocalc;
      kf[0] = nkf[0]; kf[1] = nkf[1]; kf[2] = nkf[2]; kf[3] = nkf[3];
    }
  }

  // -------- merge partials across the 4 waves (reuses P region) --------
#pragma unroll
  for (int rt = 0; rt < 4; ++rt) {
    __syncthreads();   // rt==0: all chunk work done; rt>0: previous reads done
#pragma unroll
    for (int dt = 0; dt < 4; ++dt)
      *(f32x4*)&Obuf[(w * 65 + dt * 16 + col) * 16 + q * 4] = o[rt][dt];
    if (col == 0)
      *(f32x4*)&Obuf[(w * 65 + 64) * 16 + q * 4] = lI[rt];
    __syncthreads();
    f32x4 acc = {0.f, 0.f, 0.f, 0.f};
    f32x4 lt = {0.f, 0.f, 0.f, 0.f};
#pragma unroll
    for (int w2 = 0; w2 < 4; ++w2) {
      acc += *(const f32x4*)&Obuf[(w2 * 65 + w * 16 + col) * 16 + q * 4];
      lt += *(const f32x4*)&Obuf[(w2 * 65 + 64) * 16 + q * 4];
    }
#pragma unroll
    for (int r = 0; r < 4; ++r) {
      const int trow = qg + rt * 16 + q * 4 + r;
      Y[((size_t)(b * T_ + trow)) * D_ + hh * HD_ + w * 16 + col] = f2bf(acc[r] / lt[r]);
    }
  }
}

extern "C" void kernel_launch(void* const* d_in, const int* in_sizes, int n_in,
                              void* d_out, int out_size, void* d_ws, size_t ws_size,
                              hipStream_t stream) {
  const float* x = (const float*)d_in[0];
  const float* Wqkv = (const float*)d_in[1];
  const float* bqkv = (const float*)d_in[2];
  const float* Wproj = (const float*)d_in[3];
  const float* bproj = (const float*)d_in[4];
  // d_in[5] (mask) ignored: analytic (STRIDE=256, VERTSIZE=16, causal)
  float* out = (float*)d_out;

  char* ws = (char*)d_ws;
  u16* xb     = (u16*)(ws + 0);          //  16777216
  u16* WqkvT  = (u16*)(ws + 16777216);   //   6291456
  u16* WprojT = (u16*)(ws + 23068672);   //   2097152
  u16* Qb     = (u16*)(ws + 25165824);   //  16777216 (pre-scaled by 1/8)
  u16* Kb     = (u16*)(ws + 41943040);   //  16777216
  u16* Vt     = (u16*)(ws + 58720256);   //  16777216 (V^T: [B,H,HD,T])
  u16* Y      = (u16*)(ws + 75497472);   //  16777216

  pre_all<<<dim3(12288), 256, 0, stream>>>(x, xb, Wqkv, WqkvT, Wproj, WprojT);
  gemm_db<0><<<dim3(24, 64), 256, 0, stream>>>(xb, WqkvT, bqkv, 1024, 3072, Qb, Kb, Vt);
  sparse_attn<<<dim3(64, 32), 256, 0, stream>>>(Qb, Kb, Vt, Y);
  gemm_db<1><<<dim3(8, 64), 256, 0, stream>>>(Y, WprojT, bproj, 1024, 1024, out, nullptr, nullptr);
}

// Round 10
// 239.951 us; speedup vs baseline: 1.0812x; 1.0812x over previous
//
#include <hip/hip_runtime.h>
#include <cstdint>
#include <cstddef>

typedef unsigned short u16;
typedef __attribute__((ext_vector_type(8))) short short8;
typedef __attribute__((ext_vector_type(4))) float f32x4;
typedef __attribute__((ext_vector_type(4))) unsigned short u16x4;

#define B_ 4
#define T_ 2048
#define D_ 1024
#define H_ 16
#define HD_ 64

__device__ __forceinline__ u16 f2bf(float f) {
  union { float f; unsigned i; } v; v.f = f;
  unsigned r = (v.i + 0x7FFFu + ((v.i >> 16) & 1u)) >> 16;
  return (u16)r;
}

__device__ __forceinline__ unsigned cvt_pk_bf16(float lo, float hi) {
  unsigned r;
  asm("v_cvt_pk_bf16_f32 %0, %1, %2" : "=v"(r) : "v"(lo), "v"(hi));
  return r;
}

__device__ __forceinline__ void load_lds16(const void* g, void* l) {
  __builtin_amdgcn_global_load_lds(
      (const __attribute__((address_space(1))) void*)g,
      (__attribute__((address_space(3))) void*)l, 16, 0, 0);
}

#define RBAR() asm volatile("s_barrier" ::: "memory")
#define VMC(n) asm volatile("s_waitcnt vmcnt(" #n ")" ::: "memory")

// ---------------- fused preprocessing: cvt(x) + transpose(Wqkv) + transpose(Wproj) ----------------
__global__ __launch_bounds__(256)
void pre_all(const float* __restrict__ x, u16* __restrict__ xb,
             const float* __restrict__ Wqkv, u16* __restrict__ WqkvT,
             const float* __restrict__ Wproj, u16* __restrict__ WprojT) {
  __shared__ u16 t[32][33];
  const int bid = blockIdx.x;
  const int tid = threadIdx.x;
  if (bid < 8192) {
    const size_t i = ((size_t)bid * 256 + tid) * 4;
    const f32x4 v = *(const f32x4*)(x + i);
    union { unsigned u[2]; u16x4 v4; } o;
    o.u[0] = cvt_pk_bf16(v[0], v[1]);
    o.u[1] = cvt_pk_bf16(v[2], v[3]);
    *(u16x4*)(xb + i) = o.v4;
    return;
  }
  const float* src; u16* dst; int R, C, bx, by;
  if (bid < 11264) {
    const int tb = bid - 8192;
    bx = tb % 96; by = tb / 96; src = Wqkv; dst = WqkvT; R = 1024; C = 3072;
  } else {
    const int tb = bid - 11264;
    bx = tb & 31; by = tb >> 5; src = Wproj; dst = WprojT; R = 1024; C = 1024;
  }
  const int c0 = bx * 32, r0 = by * 32;
  const int lr = tid >> 5, lc = tid & 31;
#pragma unroll
  for (int p = 0; p < 4; ++p)
    t[lr + p * 8][lc] = f2bf(src[(size_t)(r0 + lr + p * 8) * C + c0 + lc]);
  __syncthreads();
#pragma unroll
  for (int p = 0; p < 4; ++p)
    dst[(size_t)(c0 + lr + p * 8) * R + r0 + lc] = t[lc][lr + p * 8];
}

// ---------------- 128x128 GEMM: 3-buf depth-2 pipeline + n-major XCD chunking + T2 swizzle ----------------
// (round-8 proven configuration: scatter epilogue — fire-and-forget stores are
// latency-free; the round-9 coalesced-epilogue experiment regressed and is reverted.)
// XCD x (= id&7 round-robin) owns m-panels [x*8, x*8+8) x all n-panels, iterated
// n-panel-major: its 2MB A-slab stays L2-resident; B streams in 0.25MB panels.
// Pipeline: tiles t+1,t+2 in flight; steady wait vmcnt(8) drains exactly tile t.
// WAR: STAGE at iter t writes buf((t+2)%3) = buf((t-1)%3), whose reads retired
// before BAR2(t-1); its own prior loads drained by VMC at iter t-1.
template <int EPI>
__global__ __launch_bounds__(256)
void gemm_db(const u16* __restrict__ A, const u16* __restrict__ Bt,
             const float* __restrict__ bias, int K, int N,
             void* __restrict__ o0v, u16* __restrict__ o1, u16* __restrict__ o2) {
  __shared__ u16 As[3][4096];
  __shared__ u16 Bs[3][4096];
  const int tid = threadIdx.x;
  const int lane = tid & 63;
  const int w = tid >> 6;
  const int q = lane >> 4, col = lane & 15;

  const int id = blockIdx.y * gridDim.x + blockIdx.x;
  const int x = id & 7;                       // XCD (dispatch round-robin)
  const int c = id >> 3;                      // index within this XCD's chunk
  const int n0 = (c >> 3) * 128;              // n-panel-major within chunk
  const int m0 = ((x << 3) + (c & 7)) * 128;  // 8 m-panels per XCD

  const int wm = (w >> 1) * 64, wn = (w & 1) * 64;

  const int srow = tid >> 2;
  const int cb8 = ((tid & 3) ^ ((tid >> 3) & 3)) << 3;
  const u16* Ap = A + (size_t)(m0 + srow) * K + cb8;
  const u16* Bp = Bt + (size_t)(n0 + srow) * K + cb8;

  const int rs = (q ^ ((col >> 1) & 3)) << 3;

  f32x4 acc[4][4] = {};

  auto STAGE = [&](int b, int kb) {
    load_lds16(Ap + kb, &As[b][tid * 8]);
    load_lds16(Ap + (size_t)64 * K + kb, &As[b][2048 + tid * 8]);
    load_lds16(Bp + kb, &Bs[b][tid * 8]);
    load_lds16(Bp + (size_t)64 * K + kb, &Bs[b][2048 + tid * 8]);
  };

  const int NT = K >> 5;  // assumes NT >= 3
  STAGE(0, 0);
  STAGE(1, 32);
  int cur = 0, stg = 2;

  for (int t = 0; t < NT; ++t) {
    if (t + 2 < NT) {
      STAGE(stg, (t + 2) << 5);
      VMC(8);            // drain tile t's 4 loads; keep tiles t+1,t+2 in flight
    } else if (t + 1 < NT) {
      VMC(4);
    } else {
      VMC(0);
    }
    RBAR();              // BAR1: all waves' tile-t staging visible
    short8 af[4], bfr[4];
#pragma unroll
    for (int i = 0; i < 4; ++i)
      af[i] = *(const short8*)&As[cur][(wm + i * 16 + col) * 32 + rs];
#pragma unroll
    for (int j = 0; j < 4; ++j)
      bfr[j] = *(const short8*)&Bs[cur][(wn + j * 16 + col) * 32 + rs];
#pragma unroll
    for (int i = 0; i < 4; ++i)
#pragma unroll
      for (int j = 0; j < 4; ++j)
        acc[i][j] = __builtin_amdgcn_mfma_f32_16x16x32_bf16(af[i], bfr[j], acc[i][j], 0, 0, 0);
    RBAR();              // BAR2: reads of buf cur done before anyone re-stages it
    cur = (cur == 2) ? 0 : cur + 1;
    stg = (stg == 2) ? 0 : stg + 1;
  }

#pragma unroll
  for (int j = 0; j < 4; ++j) {
    const int n = n0 + wn + j * 16 + col;
    const float bv = bias[n];
    if constexpr (EPI == 0) {
      u16* q0p = (u16*)o0v;
      const int cc = n >> 10, rem = n & 1023, hh = rem >> 6, dd = rem & 63;
#pragma unroll
      for (int i = 0; i < 4; ++i) {
        const int mrow = m0 + wm + i * 16 + q * 4;
        const int b = mrow >> 11, t = mrow & 2047;
        const int bh = b * H_ + hh;
        if (cc == 0) {
#pragma unroll
          for (int r = 0; r < 4; ++r)
            q0p[((size_t)bh * T_ + t + r) * HD_ + dd] = f2bf((acc[i][j][r] + bv) * 0.125f);
        } else if (cc == 1) {
#pragma unroll
          for (int r = 0; r < 4; ++r)
            o1[((size_t)bh * T_ + t + r) * HD_ + dd] = f2bf(acc[i][j][r] + bv);
        } else {
          union { unsigned u[2]; u16x4 v4; } pk;
          pk.u[0] = cvt_pk_bf16(acc[i][j][0] + bv, acc[i][j][1] + bv);
          pk.u[1] = cvt_pk_bf16(acc[i][j][2] + bv, acc[i][j][3] + bv);
          *(u16x4*)&o2[((size_t)bh * HD_ + dd) * T_ + t] = pk.v4;
        }
      }
    } else {
      float* outp = (float*)o0v;
#pragma unroll
      for (int i = 0; i < 4; ++i) {
        const int mrow = m0 + wm + i * 16 + q * 4;
#pragma unroll
        for (int r = 0; r < 4; ++r)
          outp[(size_t)(mrow + r) * N + n] = acc[i][j][r] + bv;
      }
    }
  }
}

// ---------------- sparse causal attention (v3 — frozen) ----------------
__global__ __launch_bounds__(256)
void sparse_attn(const u16* __restrict__ Qb, const u16* __restrict__ Kb,
                 const u16* __restrict__ Vt, u16* __restrict__ Y) {
  __shared__ char smem[20480];           // P region; merge buffer overlaps after barrier
  u16* Pall = (u16*)smem;                // per-wave 64x40 u16 (5120 B)
  float* Obuf = (float*)smem;            // merge: [4 waves][65 cols][16 rows] f32 = 16640 B

  const int tid = threadIdx.x, lane = tid & 63, w = tid >> 6;
  const int q = lane >> 4, col = lane & 15;
  const int bh = blockIdx.x, qt = blockIdx.y;   // (bh,qt) for CU load balance
  const int b = bh >> 4, hh = bh & 15;
  const int qb = qt >> 2;                // 256-stride block index
  const int rb = (qt & 3) * 64;          // row base within stride block
  const int qg = qt * 64;                // global row base
  const u16* Qh = Qb + (size_t)bh * T_ * HD_;
  const u16* Kh = Kb + (size_t)bh * T_ * HD_;
  const u16* Vh = Vt + (size_t)bh * HD_ * T_;

  short8 qf[4][2];
#pragma unroll
  for (int i = 0; i < 4; ++i)
#pragma unroll
    for (int h2 = 0; h2 < 2; ++h2)
      qf[i][h2] = *(const short8*)&Qh[(size_t)(qg + i * 16 + col) * HD_ + h2 * 32 + q * 8];

  f32x4 o[4][4] = {};
  f32x4 lI[4] = {};
  const short8 ones = {0x3F80, 0x3F80, 0x3F80, 0x3F80, 0x3F80, 0x3F80, 0x3F80, 0x3F80};

  u16* P = Pall + w * 2560;

  const int ns = (qb + 1) >> 1;              // stripe chunks (2 stripe blocks each)
  const int L = ns + 2 * (qt & 3) + 2;       // + local chunks

  auto params = [&](int j, int& k0, int& k1, bool& mask1, int& localc) {
    if (j < ns) {
      k0 = (2 * j) * 256 + 240; k1 = k0 + 256;
      mask1 = (2 * j + 1 == qb); localc = -1;
    } else {
      const int c = j - ns;
      k0 = qb * 256 + c * 32; k1 = k0 + 16;
      mask1 = false; localc = c * 32;
    }
  };
  auto ldK = [&](int k0, int k1, short8* kf) {
    kf[0] = *(const short8*)&Kh[(size_t)(k0 + col) * HD_ + q * 8];
    kf[1] = *(const short8*)&Kh[(size_t)(k0 + col) * HD_ + 32 + q * 8];
    kf[2] = *(const short8*)&Kh[(size_t)(k1 + col) * HD_ + q * 8];
    kf[3] = *(const short8*)&Kh[(size_t)(k1 + col) * HD_ + 32 + q * 8];
  };

  int k0 = 0, k1 = 0, localc = -1;
  bool mask1 = false;
  short8 kf[4];
  if (w < L) { params(w, k0, k1, mask1, localc); ldK(k0, k1, kf); }

  for (int j = w; j < L; j += 4) {
    const int kvb = (q < 2) ? (k0 + q * 8) : (k1 + (q - 2) * 8);
    short8 vf[4];
#pragma unroll
    for (int dt = 0; dt < 4; ++dt)
      vf[dt] = *(const short8*)&Vh[(size_t)(dt * 16 + col) * T_ + kvb];
    int nk0 = 0, nk1 = 0, nlocalc = -1;
    bool nmask1 = false;
    short8 nkf[4];
    const bool hn = (j + 4) < L;
    if (hn) { params(j + 4, nk0, nk1, nmask1, nlocalc); ldK(nk0, nk1, nkf); }

#pragma unroll
    for (int rt = 0; rt < 4; ++rt) {
      f32x4 z = {0.f, 0.f, 0.f, 0.f};
      f32x4 s0 = __builtin_amdgcn_mfma_f32_16x16x32_bf16(qf[rt][0], kf[0], z, 0, 0, 0);
      s0 = __builtin_amdgcn_mfma_f32_16x16x32_bf16(qf[rt][1], kf[1], s0, 0, 0, 0);
      f32x4 s1 = __builtin_amdgcn_mfma_f32_16x16x32_bf16(qf[rt][0], kf[2], z, 0, 0, 0);
      s1 = __builtin_amdgcn_mfma_f32_16x16x32_bf16(qf[rt][1], kf[3], s1, 0, 0, 0);
#pragma unroll
      for (int r = 0; r < 4; ++r) {
        float p0 = __expf(s0[r]);
        float p1 = mask1 ? 0.f : __expf(s1[r]);
        if (localc >= 0) {
          const int qr = rb + rt * 16 + q * 4 + r;
          if (localc + col > qr) p0 = 0.f;
          if (localc + 16 + col > qr) p1 = 0.f;
        }
        const unsigned pc = cvt_pk_bf16(p0, p1);
        P[(rt * 16 + q * 4 + r) * 40 + col] = (u16)pc;
        P[(rt * 16 + q * 4 + r) * 40 + 16 + col] = (u16)(pc >> 16);
      }
    }
    asm volatile("s_waitcnt lgkmcnt(0)" ::: "memory");
    short8 pf[4];
#pragma unroll
    for (int rt = 0; rt < 4; ++rt)
      pf[rt] = *(const short8*)&P[(rt * 16 + col) * 40 + q * 8];
#pragma unroll
    for (int rt = 0; rt < 4; ++rt) {
#pragma unroll
      for (int dt = 0; dt < 4; ++dt)
        o[rt][dt] = __builtin_amdgcn_mfma_f32_16x16x32_bf16(pf[rt], vf[dt], o[rt][dt], 0, 0, 0);
      lI[rt] = __builtin_amdgcn_mfma_f32_16x16x32_bf16(pf[rt], ones, lI[rt], 0, 0, 0);
    }
    if (hn) {
      k0 = nk0; k1 = nk1; mask1 = nmask1; localc = nlocalc;
      kf[0] = nkf[0]; kf[1] = nkf[1]; kf[2] = nkf[2]; kf[3] = nkf[3];
    }
  }

  // -------- merge partials across the 4 waves (reuses P region) --------
#pragma unroll
  for (int rt = 0; rt < 4; ++rt) {
    __syncthreads();   // rt==0: all chunk work done; rt>0: previous reads done
#pragma unroll
    for (int dt = 0; dt < 4; ++dt)
      *(f32x4*)&Obuf[(w * 65 + dt * 16 + col) * 16 + q * 4] = o[rt][dt];
    if (col == 0)
      *(f32x4*)&Obuf[(w * 65 + 64) * 16 + q * 4] = lI[rt];
    __syncthreads();
    f32x4 acc = {0.f, 0.f, 0.f, 0.f};
    f32x4 lt = {0.f, 0.f, 0.f, 0.f};
#pragma unroll
    for (int w2 = 0; w2 < 4; ++w2) {
      acc += *(const f32x4*)&Obuf[(w2 * 65 + w * 16 + col) * 16 + q * 4];
      lt += *(const f32x4*)&Obuf[(w2 * 65 + 64) * 16 + q * 4];
    }
#pragma unroll
    for (int r = 0; r < 4; ++r) {
      const int trow = qg + rt * 16 + q * 4 + r;
      Y[((size_t)(b * T_ + trow)) * D_ + hh * HD_ + w * 16 + col] = f2bf(acc[r] / lt[r]);
    }
  }
}

extern "C" void kernel_launch(void* const* d_in, const int* in_sizes, int n_in,
                              void* d_out, int out_size, void* d_ws, size_t ws_size,
                              hipStream_t stream) {
  const float* x = (const float*)d_in[0];
  const float* Wqkv = (const float*)d_in[1];
  const float* bqkv = (const float*)d_in[2];
  const float* Wproj = (const float*)d_in[3];
  const float* bproj = (const float*)d_in[4];
  // d_in[5] (mask) ignored: analytic (STRIDE=256, VERTSIZE=16, causal)
  float* out = (float*)d_out;

  char* ws = (char*)d_ws;
  u16* xb     = (u16*)(ws + 0);          //  16777216
  u16* WqkvT  = (u16*)(ws + 16777216);   //   6291456
  u16* WprojT = (u16*)(ws + 23068672);   //   2097152
  u16* Qb     = (u16*)(ws + 25165824);   //  16777216 (pre-scaled by 1/8)
  u16* Kb     = (u16*)(ws + 41943040);   //  16777216
  u16* Vt     = (u16*)(ws + 58720256);   //  16777216 (V^T: [B,H,HD,T])
  u16* Y      = (u16*)(ws + 75497472);   //  16777216

  pre_all<<<dim3(12288), 256, 0, stream>>>(x, xb, Wqkv, WqkvT, Wproj, WprojT);
  gemm_db<0><<<dim3(24, 64), 256, 0, stream>>>(xb, WqkvT, bqkv, 1024, 3072, Qb, Kb, Vt);
  sparse_attn<<<dim3(64, 32), 256, 0, stream>>>(Qb, Kb, Vt, Y);
  gemm_db<1><<<dim3(8, 64), 256, 0, stream>>>(Y, WprojT, bproj, 1024, 1024, out, nullptr, nullptr);
}